// Round 3
// baseline (1500.319 us; speedup 1.0000x reference)
//
#include <hip/hip_runtime.h>
#include <stdint.h>

// Problem constants (from reference)
#define B_DIM 4
#define T_DIM 512
#define NTOK  2048          // B*T
#define H_DIM 2048
#define V_DIM 32000
#define BETA   0.1f
#define IGNORE_INDEX (-100)

// fallback (fp32-input) tile
#define TM    128
#define TN    128
#define BK    64
#define NCHUNK 250          // fallback chunks
// 8-phase kernel tile
#define NCH8  125           // V/256
#define NTILE8 8            // NTOK/256

typedef _Float16 f16;
typedef _Float16 half8 __attribute__((ext_vector_type(8)));
typedef float    f32x4 __attribute__((ext_vector_type(4)));

#define AS1(p) ((const __attribute__((address_space(1))) unsigned int*)(p))
#define AS3(p) ((__attribute__((address_space(3))) unsigned int*)(p))

// ---------------------------------------------------------------- fp32 -> fp16
__global__ __launch_bounds__(256) void cvt_f32_f16(const float* __restrict__ src,
                                                   f16* __restrict__ dst, int n) {
    int i = (blockIdx.x * 256 + threadIdx.x) * 8;
    if (i + 8 > n) return;
    float4 v0 = *(const float4*)(src + i);
    float4 v1 = *(const float4*)(src + i + 4);
    half8 h = { (f16)v0.x, (f16)v0.y, (f16)v0.z, (f16)v0.w,
                (f16)v1.x, (f16)v1.y, (f16)v1.z, (f16)v1.w };
    *(half8*)(dst + i) = h;
}

// ================================================================ 256^2 GEMM + LSE, BK=32, 2 blocks/CU
// R2 post-mortem: 1 resident block/CU (137 KB LDS) left all stalls exposed
// (MfmaUtil 25.6%, Occ 22%, HBM 6.5%). This version halves the K-tile to
// BK=32 (double-buffered sm = 64 KB) and aliases the epilogue reduction
// arrays into sm -> ~66 KB LDS -> 2 resident blocks/CU. Two independent
// barrier groups interleave: one block's MFMA covers the other's LDS burst
// and vmcnt drain. Same [kc][row][8] conflict-free micro-layout (R1: 0
// bank conflicts), same MFMA order (numerics identical), XCD swizzle kept.
//
// Per kt (2 phases): P1 reads A-FH0(4xb128)+B(4xb128), stages A,B(kt+1)
// (4 x global_load_lds); P2 reads A-FH1. vmcnt(0) once per kt at end-P2 --
// the drained loads were issued a full phase-pair (~800cyc) earlier.
// Overwrite safety: stage into buf^1 issued after the closing barrier of
// kt-1 (whose reads of buf^1 completed before that barrier).

#define DSR(d, a, IMM) \
    asm volatile("ds_read_b128 %0, %1 offset:%2" : "=v"(d) : "v"(a), "n"(IMM))

#define KTSTEP(BUF, KTW) do {                                                  \
    half8 af[4];                                                               \
    DSR(af[0], A_rd, (BUF) * 32768 + 0);                                       \
    DSR(af[1], A_rd, (BUF) * 32768 + 256);                                     \
    DSR(af[2], A_rd, (BUF) * 32768 + 512);                                     \
    DSR(af[3], A_rd, (BUF) * 32768 + 768);                                     \
    DSR(bfp[0], B_rd, (BUF) * 32768 + 0);                                      \
    DSR(bfp[1], B_rd, (BUF) * 32768 + 256);                                    \
    DSR(bfp[2], B_rd, (BUF) * 32768 + 512);                                    \
    DSR(bfp[3], B_rd, (BUF) * 32768 + 768);                                    \
    {                                                                          \
        const f16* sA = pA + (KTW) * 32;                                       \
        const f16* sB = pB + (KTW) * 32;                                       \
        f16* tA = dA + ((BUF) ^ 1) * 16384;                                    \
        f16* tB = dB + ((BUF) ^ 1) * 16384;                                    \
        __builtin_amdgcn_global_load_lds(AS1(sA),      AS3(tA),        16, 0, 0); \
        __builtin_amdgcn_global_load_lds(AS1(sA + 16), AS3(tA + 4096), 16, 0, 0); \
        __builtin_amdgcn_global_load_lds(AS1(sB),      AS3(tB),        16, 0, 0); \
        __builtin_amdgcn_global_load_lds(AS1(sB + 16), AS3(tB + 4096), 16, 0, 0); \
    }                                                                          \
    __builtin_amdgcn_s_barrier();                                              \
    asm volatile("s_waitcnt lgkmcnt(0)" ::: "memory");                         \
    __builtin_amdgcn_sched_barrier(0);                                         \
    __builtin_amdgcn_s_setprio(1);                                             \
    _Pragma("unroll")                                                          \
    for (int m_ = 0; m_ < 4; ++m_)                                             \
        _Pragma("unroll")                                                      \
        for (int n_ = 0; n_ < 4; ++n_)                                         \
            acc[m_][n_] = __builtin_amdgcn_mfma_f32_16x16x32_f16(              \
                af[m_], bfp[n_], acc[m_][n_], 0, 0, 0);                        \
    __builtin_amdgcn_s_setprio(0);                                             \
    __builtin_amdgcn_s_barrier();                                              \
    DSR(af[0], A_rd, (BUF) * 32768 + 1024 + 0);                                \
    DSR(af[1], A_rd, (BUF) * 32768 + 1024 + 256);                              \
    DSR(af[2], A_rd, (BUF) * 32768 + 1024 + 512);                              \
    DSR(af[3], A_rd, (BUF) * 32768 + 1024 + 768);                              \
    __builtin_amdgcn_s_barrier();                                              \
    asm volatile("s_waitcnt lgkmcnt(0)" ::: "memory");                         \
    __builtin_amdgcn_sched_barrier(0);                                         \
    __builtin_amdgcn_s_setprio(1);                                             \
    _Pragma("unroll")                                                          \
    for (int m_ = 0; m_ < 4; ++m_)                                             \
        _Pragma("unroll")                                                      \
        for (int n_ = 0; n_ < 4; ++n_)                                         \
            acc[4 + m_][n_] = __builtin_amdgcn_mfma_f32_16x16x32_f16(          \
                af[m_], bfp[n_], acc[4 + m_][n_], 0, 0, 0);                    \
    __builtin_amdgcn_s_setprio(0);                                             \
    asm volatile("s_waitcnt vmcnt(0)" ::: "memory");                           \
    __builtin_amdgcn_s_barrier();                                              \
} while (0)

__global__ __launch_bounds__(512, 2) void gemm_lse8(
    const f16* __restrict__ x0, const f16* __restrict__ x1,
    const f16* __restrict__ w0, const f16* __restrict__ w1,
    const int* __restrict__ y,
    float2* __restrict__ pMS,
    float* __restrict__ tokL)
{
    // XCD-bijective swizzle: 2000 wgs, 2000 % 8 == 0.
    const int orig = blockIdx.x;
    const int wg   = (orig & 7) * 250 + (orig >> 3);
    const int tile = wg & 7;            // 0..7  (8 token tiles, fastest)
    const int rest = wg >> 3;           // 0..249
    const int chunk = rest % NCH8;      // 0..124
    const int model = rest / NCH8;      // 0..1

    const f16* Xp = model ? x1 : x0;
    const f16* Wp = model ? w1 : w0;

    const int tid  = threadIdx.x;
    const int lane = tid & 63;
    const int wave = tid >> 6;
    const int wm   = wave >> 2;         // 0..1: 128-row half (tokens)
    const int wn   = wave & 3;          // 0..3: 64-col quarter (vocab)

    // [buf][mat][kc(4)][row(256)][8] f16 = 64 KiB; epilogue redM/redS alias it.
    __shared__ __align__(16) f16 sm[2][2][4][256][8];
    __shared__ int ys[256];

    const int rowA0 = tile * 256;
    const int rowB0 = chunk * 256;

    f32x4 acc[8][4];
#pragma unroll
    for (int i = 0; i < 8; ++i)
#pragma unroll
        for (int j = 0; j < 4; ++j) acc[i][j] = (f32x4){0.f, 0.f, 0.f, 0.f};

    // staging map: slot = ld*512+tid -> kc = slot>>8, row = slot&255.
    const int rS = tid & 255;
    const int cS = tid >> 8;            // 0..1
    const f16* pA = Xp + (size_t)(rowA0 + rS) * H_DIM + cS * 8;
    const f16* pB = Wp + (size_t)(rowB0 + rS) * H_DIM + cS * 8;
    f16* dA = &sm[0][0][0][0][0] + (size_t)tid * 8;
    f16* dB = dA + 8192;

    // fragment-read LDS byte bases (conflict-free pattern, R1-measured)
    auto* smp3 = (__attribute__((address_space(3))) f16*)&sm[0][0][0][0][0];
    const unsigned smBase = (unsigned)(uintptr_t)smp3;
    const unsigned A_rd = smBase + ((unsigned)(lane >> 4) << 12)
                        + (((unsigned)(wm * 128 + (lane & 15))) << 4);
    const unsigned B_rd = smBase + 16384u + ((unsigned)(lane >> 4) << 12)
                        + (((unsigned)(wn * 64 + (lane & 15))) << 4);

    half8 bfp[4];   // B frags persist across the P1/P2 phase pair

    // ---- prologue: y load + stage kt0 into buf0, full drain
    int yreg = 0;
    if (tid < 256) yreg = y[rowA0 + tid];
    __builtin_amdgcn_global_load_lds(AS1(pA),      AS3(dA),        16, 0, 0);
    __builtin_amdgcn_global_load_lds(AS1(pA + 16), AS3(dA + 4096), 16, 0, 0);
    __builtin_amdgcn_global_load_lds(AS1(pB),      AS3(dB),        16, 0, 0);
    __builtin_amdgcn_global_load_lds(AS1(pB + 16), AS3(dB + 4096), 16, 0, 0);
    asm volatile("s_waitcnt vmcnt(0)" ::: "memory");
    if (tid < 256) ys[tid] = yreg;
    __builtin_amdgcn_s_barrier();

    // ---- main loop: 64 K-tiles (BK=32), buf parity compile-time
#pragma unroll 1
    for (int it = 0; it < 32; ++it) {
        KTSTEP(0, (2 * it + 1) & 63);
        KTSTEP(1, (2 * it + 2) & 63);
    }

    // ---- epilogue ----
    // All stages drained (final vmcnt(0)+barrier) -> safe to alias sm.
    float* redM = (float*)&sm[0][0][0][0][0];            // [256][4]
    float* redS = (float*)(&sm[0][0][0][0][0] + 2048);   // +4096 B

    // C/D layout: col = lane&15 (vocab), row = (lane>>4)*4 + reg (token)
    // 1) target logit — all acc indices compile-time constant
#pragma unroll
    for (int i2 = 0; i2 < 8; ++i2) {
#pragma unroll
        for (int r = 0; r < 4; ++r) {
            int rl = wm * 128 + i2 * 16 + ((lane >> 4) << 2) + r;
            int t = ys[rl];
            int trel = t - (rowB0 + wn * 64);
#pragma unroll
            for (int j = 0; j < 4; ++j) {
                if (trel == j * 16 + (lane & 15))
                    tokL[model * NTOK + rowA0 + rl] = acc[i2][j][r];
            }
        }
    }

    // 2) per-row (max, sumexp) over this wave's 64 columns
#pragma unroll
    for (int i2 = 0; i2 < 8; ++i2) {
#pragma unroll
        for (int r = 0; r < 4; ++r) {
            float mx = fmaxf(fmaxf(acc[i2][0][r], acc[i2][1][r]),
                             fmaxf(acc[i2][2][r], acc[i2][3][r]));
            for (int m = 1; m < 16; m <<= 1) mx = fmaxf(mx, __shfl_xor(mx, m, 64));
            float s = 0.f;
#pragma unroll
            for (int j = 0; j < 4; ++j) s += __expf(acc[i2][j][r] - mx);
            for (int m = 1; m < 16; m <<= 1) s += __shfl_xor(s, m, 64);
            if ((lane & 15) == 0) {
                int rl = wm * 128 + i2 * 16 + ((lane >> 4) << 2) + r;
                redM[rl * 4 + wn] = mx;
                redS[rl * 4 + wn] = s;
            }
        }
    }
    __syncthreads();
    if (tid < 256) {
        float M = redM[tid * 4 + 0], S = redS[tid * 4 + 0];
#pragma unroll
        for (int q = 1; q < 4; ++q) {
            float m2 = redM[tid * 4 + q], s2 = redS[tid * 4 + q];
            float Mn = fmaxf(M, m2);
            S = S * __expf(M - Mn) + s2 * __expf(m2 - Mn);
            M = Mn;
        }
        size_t o = ((size_t)model * NTOK + rowA0 + tid) * NCH8 + chunk;
        pMS[o] = make_float2(M, S);
    }
}

// ================================================================ fallback fp32-input GEMM (R1-proven)
__global__ __launch_bounds__(256, 3) void gemm_lse_f32(
    const float* __restrict__ x0, const float* __restrict__ x1,
    const float* __restrict__ w0, const float* __restrict__ w1,
    const int* __restrict__ y,
    float2* __restrict__ pMS,
    float* __restrict__ tokL)
{
    const int tile  = blockIdx.x;
    const int chunk = blockIdx.y;
    const int model = blockIdx.z;
    const float* Xp = model ? x1 : x0;
    const float* Wp = model ? w1 : w0;

    const int tid  = threadIdx.x;
    const int lane = tid & 63;
    const int wave = tid >> 6;
    const int wm   = wave >> 1;
    const int wn   = wave & 1;

    __shared__ __align__(16) f16 As[8][TM][8];
    __shared__ __align__(16) f16 Bs[8][TN][8];
    __shared__ float redM[TM][2];
    __shared__ float redS[TM][2];
    __shared__ int   ys[TM];

    if (tid < TM) ys[tid] = y[tile * TM + tid];

    f32x4 acc[4][4];
#pragma unroll
    for (int i = 0; i < 4; ++i)
#pragma unroll
        for (int j = 0; j < 4; ++j) acc[i][j] = (f32x4){0.f, 0.f, 0.f, 0.f};

    const int rowA0 = tile * TM;
    const int rowB0 = chunk * TN;
    const int kc    = lane >> 4;
    const int rS = tid & 127;
    const int cS = tid >> 7;

    const float* pA = Xp + (size_t)(rowA0 + rS) * H_DIM + cS * 8;
    const float* pB = Wp + (size_t)(rowB0 + rS) * H_DIM + cS * 8;
    f16* dA = &As[0][0][0] + tid * 8;
    f16* dB = &Bs[0][0][0] + tid * 8;

    for (int k0 = 0; k0 < H_DIM; k0 += BK) {
#pragma unroll
        for (int i = 0; i < 4; ++i) {
            float4 v0 = *(const float4*)(pA + i * 16);
            float4 v1 = *(const float4*)(pA + i * 16 + 4);
            half8 h = { (f16)v0.x, (f16)v0.y, (f16)v0.z, (f16)v0.w,
                        (f16)v1.x, (f16)v1.y, (f16)v1.z, (f16)v1.w };
            *(half8*)(dA + i * 2048) = h;
        }
#pragma unroll
        for (int i = 0; i < 4; ++i) {
            float4 v0 = *(const float4*)(pB + i * 16);
            float4 v1 = *(const float4*)(pB + i * 16 + 4);
            half8 h = { (f16)v0.x, (f16)v0.y, (f16)v0.z, (f16)v0.w,
                        (f16)v1.x, (f16)v1.y, (f16)v1.z, (f16)v1.w };
            *(half8*)(dB + i * 2048) = h;
        }
        pA += BK; pB += BK;
        __syncthreads();

#pragma unroll
        for (int p = 0; p < 2; ++p) {
            half8 af[4], bfr[4];
#pragma unroll
            for (int i = 0; i < 4; ++i)
                af[i] = *(const half8*)As[p * 4 + kc][wm * 64 + i * 16 + (lane & 15)];
#pragma unroll
            for (int j = 0; j < 4; ++j)
                bfr[j] = *(const half8*)Bs[p * 4 + kc][wn * 64 + j * 16 + (lane & 15)];
#pragma unroll
            for (int i = 0; i < 4; ++i)
#pragma unroll
                for (int j = 0; j < 4; ++j)
                    acc[i][j] = __builtin_amdgcn_mfma_f32_16x16x32_f16(af[i], bfr[j], acc[i][j], 0, 0, 0);
        }
        __syncthreads();
    }

#pragma unroll
    for (int i = 0; i < 4; ++i) {
#pragma unroll
        for (int r = 0; r < 4; ++r) {
            int rl = wm * 64 + i * 16 + ((lane >> 4) << 2) + r;
            int t = ys[rl];
            int trel = t - (rowB0 + wn * 64);
#pragma unroll
            for (int j = 0; j < 4; ++j) {
                if (trel == j * 16 + (lane & 15))
                    tokL[model * NTOK + rowA0 + rl] = acc[i][j][r];
            }
        }
    }

#pragma unroll
    for (int i = 0; i < 4; ++i) {
#pragma unroll
        for (int r = 0; r < 4; ++r) {
            float mx = fmaxf(fmaxf(acc[i][0][r], acc[i][1][r]),
                             fmaxf(acc[i][2][r], acc[i][3][r]));
            for (int m = 1; m < 16; m <<= 1) mx = fmaxf(mx, __shfl_xor(mx, m, 64));
            float s = 0.f;
#pragma unroll
            for (int j = 0; j < 4; ++j) s += __expf(acc[i][j][r] - mx);
            for (int m = 1; m < 16; m <<= 1) s += __shfl_xor(s, m, 64);
            if ((lane & 15) == 0) {
                int rl = wm * 64 + i * 16 + ((lane >> 4) << 2) + r;
                redM[rl][wn] = mx;
                redS[rl][wn] = s;
            }
        }
    }
    __syncthreads();
    if (tid < TM) {
        float m0 = redM[tid][0], m1 = redM[tid][1];
        float s0 = redS[tid][0], s1 = redS[tid][1];
        float M = fmaxf(m0, m1);
        float S = s0 * __expf(m0 - M) + s1 * __expf(m1 - M);
        size_t o = ((size_t)model * NTOK + tile * TM + tid) * NCHUNK + chunk;
        pMS[o] = make_float2(M, S);
    }
}

// ---------------------------------------------------------------- combine chunk partials -> per-token logp
__global__ __launch_bounds__(256) void lse_reduce(const float2* __restrict__ pMS,
                                                  const float* __restrict__ tokL,
                                                  const int* __restrict__ y,
                                                  float* __restrict__ logp,
                                                  int nchunk) {
    int g = blockIdx.x * 4 + (threadIdx.x >> 6);   // 0..4095 = model*NTOK + token
    int lane = threadIdx.x & 63;
    const float2* base = pMS + (size_t)g * nchunk;
    float M = -1e30f, S = 0.f;
    for (int c = lane; c < nchunk; c += 64) {
        float2 ms = base[c];
        if (ms.x > M) { S = S * __expf(M - ms.x) + ms.y; M = ms.x; }
        else          { S += ms.y * __expf(ms.x - M); }
    }
#pragma unroll
    for (int off = 1; off < 64; off <<= 1) {
        float Mo = __shfl_xor(M, off, 64);
        float So = __shfl_xor(S, off, 64);
        float Mn = fmaxf(M, Mo);
        S = S * __expf(M - Mn) + So * __expf(Mo - Mn);
        M = Mn;
    }
    if (lane == 0) {
        float lse = M + logf(S);
        int token = g & (NTOK - 1);
        int t = y[token];
        logp[g] = (t == IGNORE_INDEX) ? 0.f : (tokL[g] - lse);
    }
}

// ---------------------------------------------------------------- final KTO scalar
__device__ __forceinline__ float sigf(float z) { return 1.f / (1.f + expf(-z)); }

__global__ void final_loss(const float* __restrict__ logp,
                           const int* __restrict__ y,
                           float* __restrict__ out) {
    int lane = threadIdx.x;  // 64 threads, one wave
    float avg[2][4];
    for (int model = 0; model < 2; ++model)
        for (int b = 0; b < 4; ++b) {
            float s = 0.f, c = 0.f;
            for (int t = lane; t < T_DIM; t += 64) {
                int token = b * T_DIM + t;
                if (y[token] != IGNORE_INDEX) { s += logp[model * NTOK + token]; c += 1.f; }
            }
            for (int m = 1; m < 64; m <<= 1) {
                s += __shfl_xor(s, m, 64);
                c += __shfl_xor(c, m, 64);
            }
            avg[model][b] = s / c;
        }
    if (lane == 0) {
        float loss = 0.f;
        for (int b = 0; b < 2; ++b) {
            float lr = avg[0][b] - avg[1][b];
            loss += 1.f - sigf(BETA * lr);
        }
        for (int b = 2; b < 4; ++b) {
            float lr = avg[0][b] - avg[1][b];
            loss += 1.f - sigf(-BETA * lr);
        }
        out[0] = loss * 0.5f;
    }
}

// ---------------------------------------------------------------- launch
extern "C" void kernel_launch(void* const* d_in, const int* in_sizes, int n_in,
                              void* d_out, int out_size, void* d_ws, size_t ws_size,
                              hipStream_t stream) {
    const float* x  = (const float*)d_in[0];
    const float* rx = (const float*)d_in[1];
    const int*   y  = (const int*)d_in[2];
    const float* W  = (const float*)d_in[3];
    const float* rW = (const float*)d_in[4];
    float* out = (float*)d_out;

    const size_t nX = (size_t)NTOK * H_DIM;   // 4,194,304
    const size_t nW = (size_t)V_DIM * H_DIM;  // 65,536,000

    char* p = (char*)d_ws;
    float2* pMS = (float2*)p; p += (size_t)2 * NTOK * NCHUNK * 8;   // sized for max stride
    float* tokL = (float*)p;  p += (size_t)2 * NTOK * 4;
    float* logp = (float*)p;  p += (size_t)2 * NTOK * 4;
    size_t base = (size_t)(p - (char*)d_ws);
    size_t need_fast = base + 2 * nX * 2 + 2 * nW * 2;

    if (ws_size >= need_fast) {
        f16* xb  = (f16*)p; p += nX * 2;
        f16* rxb = (f16*)p; p += nX * 2;
        f16* wb  = (f16*)p; p += nW * 2;
        f16* rwb = (f16*)p; p += nW * 2;
        cvt_f32_f16<<<(int)(nX / 8 / 256), 256, 0, stream>>>(x,  xb,  (int)nX);
        cvt_f32_f16<<<(int)(nX / 8 / 256), 256, 0, stream>>>(rx, rxb, (int)nX);
        cvt_f32_f16<<<(int)(nW / 8 / 256), 256, 0, stream>>>(W,  wb,  (int)nW);
        cvt_f32_f16<<<(int)(nW / 8 / 256), 256, 0, stream>>>(rW, rwb, (int)nW);
        gemm_lse8<<<dim3(NTILE8 * NCH8 * 2), 512, 0, stream>>>(xb, rxb, wb, rwb, y, pMS, tokL);
        lse_reduce<<<1024, 256, 0, stream>>>(pMS, tokL, y, logp, NCH8);
    } else {
        gemm_lse_f32<<<dim3(NTOK / TM, NCHUNK, 2), 256, 0, stream>>>(x, rx, W, rW, y, pMS, tokL);
        lse_reduce<<<1024, 256, 0, stream>>>(pMS, tokL, y, logp, NCHUNK);
    }
    final_loss<<<1, 64, 0, stream>>>(logp, y, out);
}